// Round 1
// baseline (229.776 us; speedup 1.0000x reference)
//
#include <hip/hip_runtime.h>

// C[n][m] = A[n] * B[n][m]   (N=32768, M=4096, fp32)
// Pure streaming row-scale: memory-bound, target ~6.3 TB/s HBM.
// float4 vectorized; row = f4_index >> 10 since M/4 = 1024 (pow2).

#ifndef M_DIM_LOG2_F4
#define M_DIM_LOG2_F4 10   // log2(4096/4)
#endif

__global__ __launch_bounds__(256) void rowscale_f4(
    const float* __restrict__ A,
    const float4* __restrict__ B4,
    float4* __restrict__ C4,
    long long n_f4)
{
    long long stride = (long long)gridDim.x * blockDim.x;
    for (long long i = (long long)blockIdx.x * blockDim.x + threadIdx.x;
         i < n_f4; i += stride)
    {
        float a = A[i >> M_DIM_LOG2_F4];
        float4 b = B4[i];
        float4 c;
        c.x = a * b.x;
        c.y = a * b.y;
        c.z = a * b.z;
        c.w = a * b.w;
        C4[i] = c;
    }
}

extern "C" void kernel_launch(void* const* d_in, const int* in_sizes, int n_in,
                              void* d_out, int out_size, void* d_ws, size_t ws_size,
                              hipStream_t stream)
{
    const float* A = (const float*)d_in[0];
    const float4* B4 = (const float4*)d_in[1];
    float4* C4 = (float4*)d_out;

    long long n_f4 = (long long)out_size / 4;   // 32768*4096/4 = 33,554,432

    const int block = 256;
    // Memory-bound: cap grid at ~8 blocks/CU * 256 CUs and grid-stride.
    int grid = (int)((n_f4 + block - 1) / block);
    if (grid > 2048) grid = 2048;

    rowscale_f4<<<grid, block, 0, stream>>>(A, B4, C4, n_f4);
}

// Round 3
// 180.495 us; speedup vs baseline: 1.2730x; 1.2730x over previous
//
#include <hip/hip_runtime.h>

// C[n][m] = A[n] * B[n][m]   (N=32768, M=4096, fp32)
// One block per row: A[row] is wave-uniform (scalar load), vector pipe
// carries pure stream traffic. Non-temporal load/store to bypass L2
// pollution (B,C = 1 GB stream through 32 MB L2 with zero reuse).
// Uses clang ext_vector float4 so __builtin_nontemporal_* accepts it.

typedef float f32x4 __attribute__((ext_vector_type(4)));

#define M_F4 1024   // 4096 / 4 float4s per row

__global__ __launch_bounds__(256) void rowscale_rows(
    const float* __restrict__ A,
    const f32x4* __restrict__ B4,
    f32x4* __restrict__ C4)
{
    const int row = blockIdx.x;              // uniform per block
    const float a = A[row];                  // -> s_load (wave-uniform)

    const f32x4* __restrict__ b = B4 + (size_t)row * M_F4;
    f32x4* __restrict__ c = C4 + (size_t)row * M_F4;

    const int t = threadIdx.x;

    f32x4 v[4];
#pragma unroll
    for (int k = 0; k < 4; ++k)
        v[k] = __builtin_nontemporal_load(&b[t + k * 256]);

#pragma unroll
    for (int k = 0; k < 4; ++k)
        __builtin_nontemporal_store(v[k] * a, &c[t + k * 256]);
}

extern "C" void kernel_launch(void* const* d_in, const int* in_sizes, int n_in,
                              void* d_out, int out_size, void* d_ws, size_t ws_size,
                              hipStream_t stream)
{
    const float* A = (const float*)d_in[0];
    const f32x4* B4 = (const f32x4*)d_in[1];
    f32x4* C4 = (f32x4*)d_out;

    const int n_rows = in_sizes[0];          // 32768

    rowscale_rows<<<n_rows, 256, 0, stream>>>(A, B4, C4);
}